// Round 1
// 4226.306 us; speedup vs baseline: 1.0287x; 1.0287x over previous
//
#include <hip/hip_runtime.h>
#include <math.h>

#define B_   32
#define S_   1024
#define DIN  512
#define DH   512
#define KTOT 1024          // DH (H part) + DIN (x part)
#define NWG  64
#define TPB  256
#define NB   4             // rotating H-exchange buffers
#define HB64 4096          // u64 per buffer: 2 groups x 2048
#define RPAD 17            // R row stride in floats: conflict-free scalar access

typedef short short8 __attribute__((ext_vector_type(8)));  // 8 bf16 (4 VGPRs)
typedef float f32x4  __attribute__((ext_vector_type(4)));
typedef unsigned long long u64;

#define SENT 0xFFFFFFFFFFFFFFFFULL   // 4x bf16 NaN; |H|<1 so never produced by f2bf

__device__ __forceinline__ unsigned short f2bf(float f) {
  unsigned u = __float_as_uint(f);
  u += 0x7FFFu + ((u >> 16) & 1u);   // RNE
  return (unsigned short)(u >> 16);
}

__device__ __forceinline__ float sigmoid_f(float z) {
  return 1.f / (1.f + __expf(-z));
}
__device__ __forceinline__ float tanh_f(float z) {
  float e = __expf(-2.f * fabsf(z));
  float t = (1.f - e) / (1.f + e);
  return z < 0.f ? -t : t;
}

__device__ __forceinline__ f32x4 mfma16(short8 a, short8 b, f32x4 c) {
  return __builtin_amdgcn_mfma_f32_16x16x32_bf16(a, b, c, 0, 0, 0);
}

__device__ __forceinline__ u64 cload(const u64* p) {
  return __hip_atomic_load(p, __ATOMIC_RELAXED, __HIP_MEMORY_SCOPE_AGENT);
}
__device__ __forceinline__ void cstore(u64* p, u64 v) {
  __hip_atomic_store(p, v, __ATOMIC_RELAXED, __HIP_MEMORY_SCOPE_AGENT);
}

// B-operand layout: Bws[idx 0..31][c 0..63][k 0..1023], c = gate*16 + jj,
// hcol = idx*16 + jj, k<512 -> Wh, else Wx. Shared by both batch groups.
__global__ void k_prep(const float* __restrict__ Whi, const float* __restrict__ Whf,
                       const float* __restrict__ Who, const float* __restrict__ Whc,
                       const float* __restrict__ Wxi, const float* __restrict__ Wxf,
                       const float* __restrict__ Wxo, const float* __restrict__ Wxc,
                       unsigned short* __restrict__ Bws, unsigned* __restrict__ bar) {
  int chunk = blockIdx.x * TPB + threadIdx.x;      // 0..262143, 8 elems each
  int idx = chunk >> 13;
  int rem = chunk & 8191;
  int c   = rem >> 7;             // gate*16 + jj
  int k8  = (rem & 127) << 3;
  int g    = c >> 4;
  int hcol = (idx << 4) | (c & 15);
  const float* Wh = (g == 0) ? Whi : (g == 1) ? Whf : (g == 2) ? Who : Whc;
  const float* Wx = (g == 0) ? Wxi : (g == 1) ? Wxf : (g == 2) ? Wxo : Wxc;
  short8 sv;
  #pragma unroll
  for (int j = 0; j < 8; ++j) {
    int k = k8 + j;
    float f = (k < DH) ? Wh[(size_t)k * DH + hcol] : Wx[(size_t)(k - DH) * DH + hcol];
    sv[j] = (short)f2bf(f);
  }
  *(short8*)(Bws + (size_t)chunk * 8) = sv;
  if (blockIdx.x == 0 && threadIdx.x < 256) bar[threadIdx.x] = 0;  // reset startup barrier
}

// Persistent fused LSTM scan. 2 independent batch-groups of 32 WGs (16 batches,
// M=16 MFMA). H exchange: fragment-direct layout in LLC — each wave polls only
// its K-quarter (8 u64/thread, 8 producer WGs) straight into MFMA A-fragments.
// 4 rotating buffers so the re-sentinel (issued post-SYNC-A, where all quarters
// are provably consumed) is drained a full step before the publish waitcnt.
__launch_bounds__(TPB, 1)
__global__ void k_scan(const float* __restrict__ x,
                       const float* __restrict__ bi, const float* __restrict__ bfv,
                       const float* __restrict__ bo, const float* __restrict__ bc,
                       const unsigned short* __restrict__ Bws,
                       u64* __restrict__ hbuf64,   // NB buffers of [2 groups][2048] u64
                       unsigned* __restrict__ bar, // 8 startup counters, 128B apart
                       float* __restrict__ out) {
  __shared__ float R[4 * 64 * RPAD];         // per-wave partial accumulators

  const int tid  = threadIdx.x;
  const int w    = blockIdx.x;
  const int lane = tid & 63;
  const int wv   = tid >> 6;                 // wave 0..3 = K-quarter owner
  const int g    = w >> 5;                   // batch group 0..1
  const int idx  = w & 31;                   // H-col block 0..31

  const int eb   = tid >> 4;                 // group-local batch row 0..15
  const int ej   = tid & 15;                 // local hcol 0..15
  const int hcol = (idx << 4) | ej;
  const int batch = (g << 4) | eb;

  const int r0 = lane & 15;
  const int kq = (lane >> 4) << 3;

  const float pbi = bi[hcol], pbf = bfv[hcol], pbo = bo[hcol], pbc = bc[hcol];
  float Creg = 0.f;

  // publisher slot for this thread's 4-col quad (only tid%4==0 stores)
  int ch   = (idx << 4) | (ej & ~3);         // quad base H-col 0..511
  int wvt  = ch >> 7;                        // consumer wave (K-quarter)
  int cq   = ch & 127;
  int ksq  = cq >> 5;
  int kqi  = (cq & 31) >> 3;
  int uh   = (cq >> 2) & 1;
  const int pslot = (g << 11) | (wvt << 9) | (((ksq << 1) | uh) << 6) | (kqi << 4) | eb;

  // consumer poll base: slot (g, wv, i, lane) holds H[lane&15][wv*128+ks*32+(lane>>4)*8+uh*4 ..+3]
  const int cbase = (g << 11) | (wv << 9) | lane;

  // weights -> registers for the whole scan (128 VGPRs)
  short8 bfrag[8][4];
  {
    const int col0 = lane & 15;
    #pragma unroll
    for (int ks = 0; ks < 8; ++ks) {
      int kb = (ks < 4) ? (wv * 128 + ks * 32 + kq)
                        : (DH + wv * 128 + (ks - 4) * 32 + kq);
      #pragma unroll
      for (int nf = 0; nf < 4; ++nf) {
        int col = nf * 16 + col0;
        bfrag[ks][nf] = *(const short8*)(Bws + ((size_t)((idx << 6) | col) * KTOT + kb));
      }
    }
  }

  // pre-sentinel buf0 & buf1 (first in-loop sentinel targets buf2), then
  // startup barrier: all sentinels at LLC before anyone can publish/poll
  // (also covers workspace 0xAA poison).
  if ((tid & 3) == 0) {
    cstore(&hbuf64[pslot], SENT);
    cstore(&hbuf64[HB64 + pslot], SENT);
  }
  __builtin_amdgcn_s_waitcnt(0);
  __syncthreads();
  if (tid == 0) {
    __hip_atomic_fetch_add(&bar[(w & 7) * 32], 1u,
                           __ATOMIC_RELAXED, __HIP_MEMORY_SCOPE_AGENT);
    for (;;) {
      unsigned s = 0;
      #pragma unroll
      for (int i = 0; i < 8; ++i)
        s += __hip_atomic_load(&bar[i * 32], __ATOMIC_RELAXED, __HIP_MEMORY_SCOPE_AGENT);
      if (s >= (unsigned)NWG) break;
      __builtin_amdgcn_s_sleep(1);
    }
  }
  __syncthreads();

  // x A-fragment base for this lane (row = g*16 + r0, K-quarter wv, sub-slice kq)
  const float* xlane = x + (size_t)((g << 4) | r0) * (S_ * DIN) + (wv * 128 + kq);

  f32x4 acc[4];
  // x-part for t=0, straight from global into fragments
  {
    #pragma unroll
    for (int nf = 0; nf < 4; ++nf) acc[nf] = (f32x4){0.f, 0.f, 0.f, 0.f};
    #pragma unroll
    for (int ksx = 0; ksx < 4; ++ksx) {
      float4 v0 = *(const float4*)(xlane + ksx * 32);
      float4 v1 = *(const float4*)(xlane + ksx * 32 + 4);
      short8 ax;
      ax[0] = (short)f2bf(v0.x); ax[1] = (short)f2bf(v0.y);
      ax[2] = (short)f2bf(v0.z); ax[3] = (short)f2bf(v0.w);
      ax[4] = (short)f2bf(v1.x); ax[5] = (short)f2bf(v1.y);
      ax[6] = (short)f2bf(v1.z); ax[7] = (short)f2bf(v1.w);
      #pragma unroll
      for (int nf = 0; nf < 4; ++nf) acc[nf] = mfma16(ax, bfrag[4 + ksx][nf], acc[nf]);
    }
  }

  for (int t = 0; t < S_; ++t) {
    if (t > 0) {
      // ---- per-wave poll of this wave's K-quarter of H_{t-1}: detect + load
      // land directly in MFMA A-fragments (8 u64/thread, 8 producer WGs) ----
      const u64* hr = hbuf64 + (size_t)((t - 1) & 3) * HB64;
      u64 tmp[8];
      unsigned pending = 0xFFu;
      #pragma unroll
      for (int i = 0; i < 8; ++i) tmp[i] = cload(&hr[cbase + (i << 6)]);
      #pragma unroll
      for (int i = 0; i < 8; ++i) if (tmp[i] != SENT) pending &= ~(1u << i);
      while (pending) {
        #pragma unroll
        for (int i = 0; i < 8; ++i)
          if (pending & (1u << i)) tmp[i] = cload(&hr[cbase + (i << 6)]);
        #pragma unroll
        for (int i = 0; i < 8; ++i)
          if ((pending & (1u << i)) && tmp[i] != SENT) pending &= ~(1u << i);
      }
      // ---- H-part MFMA straight from polled registers ----
      #pragma unroll
      for (int ks = 0; ks < 4; ++ks) {
        union { u64 q[2]; short8 s; } cv;
        cv.q[0] = tmp[2 * ks]; cv.q[1] = tmp[2 * ks + 1];
        #pragma unroll
        for (int nf = 0; nf < 4; ++nf) acc[nf] = mfma16(cv.s, bfrag[ks][nf], acc[nf]);
      }
    }

    // partials to LDS (scalar stores, stride 17 -> conflict-free)
    {
      float* rp = &R[tid * RPAD];
      #pragma unroll
      for (int nf = 0; nf < 4; ++nf) {
        #pragma unroll
        for (int m = 0; m < 4; ++m) rp[nf * 4 + m] = acc[nf][m];
      }
    }
    __syncthreads();   // SYNC A: all 4 quarters of H_{t-1} consumed, R complete

    // re-sentinel buf (t+2)%4: safe only post-SYNC-A (=> every group WG has
    // published H_{t-1} => finished reading that buffer's H_{t-2}); drained by
    // the publish waitcnt at t+1 — a full step of slack, zero critical cost.
    if (t + 2 < S_ && (tid & 3) == 0)
      cstore(&hbuf64[(size_t)((t + 2) & 3) * HB64 + pslot], SENT);

    // ---- cross-wave K reduction + gate math ----
    float pre0 = 0.f, pre1 = 0.f, pre2 = 0.f, pre3 = 0.f;
    {
      int ln = ((eb >> 2) << 4) | ej;
      int rg = eb & 3;
      #pragma unroll
      for (int v = 0; v < 4; ++v) {
        const float* q = &R[(v * 64 + ln) * RPAD + rg];
        pre0 += q[0]; pre1 += q[4]; pre2 += q[8]; pre3 += q[12];
      }
    }
    float I  = sigmoid_f(pre0 + pbi);
    float F  = sigmoid_f(pre1 + pbf);
    float O  = sigmoid_f(pre2 + pbo);
    float Cc = tanh_f(pre3 + pbc);
    Creg = F * Creg + I * Cc;
    float H = O * tanh_f(Creg);

    // pack 4 neighboring lanes (same batch row, consecutive hcols) via shuffles
    unsigned hv = f2bf(H);
    int lb = lane & ~3;
    u64 p = (u64)__shfl(hv, lb) | ((u64)__shfl(hv, lb | 1) << 16)
          | ((u64)__shfl(hv, lb | 2) << 32) | ((u64)__shfl(hv, lb | 3) << 48);

    if (t + 1 < S_) {
      // waitcnt drains only step-old stores (sentinel from t-1, out from t-1):
      // effectively free. Ensures sentinel-buf(t+1) at LLC before data-buf(t)
      // becomes visible (poison-safety chain for the next buffer).
      __builtin_amdgcn_s_waitcnt(0);
      if ((tid & 3) == 0)
        cstore(&hbuf64[(size_t)(t & 3) * HB64 + pslot], p);
    }

    // out-store AFTER publish: HBM write-ack never sits on the exchange path
    out[(size_t)batch * (S_ * DH) + (size_t)t * DH + hcol] = H;
    if (t == S_ - 1) out[(size_t)(B_ * S_ * DH) + (size_t)batch * DH + hcol] = H;  // Hf

    if (t + 1 < S_) {
      // ---- x-part for t+1 straight from global (L3-resident) into fragments;
      // overlaps other WGs' publish->visibility latency ----
      #pragma unroll
      for (int nf = 0; nf < 4; ++nf) acc[nf] = (f32x4){0.f, 0.f, 0.f, 0.f};
      const float* xt = xlane + (size_t)(t + 1) * DIN;
      #pragma unroll
      for (int ksx = 0; ksx < 4; ++ksx) {
        float4 v0 = *(const float4*)(xt + ksx * 32);
        float4 v1 = *(const float4*)(xt + ksx * 32 + 4);
        short8 ax;
        ax[0] = (short)f2bf(v0.x); ax[1] = (short)f2bf(v0.y);
        ax[2] = (short)f2bf(v0.z); ax[3] = (short)f2bf(v0.w);
        ax[4] = (short)f2bf(v1.x); ax[5] = (short)f2bf(v1.y);
        ax[6] = (short)f2bf(v1.z); ax[7] = (short)f2bf(v1.w);
        #pragma unroll
        for (int nf = 0; nf < 4; ++nf) acc[nf] = mfma16(ax, bfrag[4 + ksx][nf], acc[nf]);
      }
    }
    __syncthreads();   // SYNC B: separates R reads (step t) from R writes (t+1)
  }
}

extern "C" void kernel_launch(void* const* d_in, const int* in_sizes, int n_in,
                              void* d_out, int out_size, void* d_ws, size_t ws_size,
                              hipStream_t stream) {
  const float* x   = (const float*)d_in[0];
  const float* Wxi = (const float*)d_in[1];
  const float* Whi = (const float*)d_in[2];
  const float* bi  = (const float*)d_in[3];
  const float* Wxf = (const float*)d_in[4];
  const float* Whf = (const float*)d_in[5];
  const float* bfv = (const float*)d_in[6];
  const float* Wxo = (const float*)d_in[7];
  const float* Who = (const float*)d_in[8];
  const float* bo  = (const float*)d_in[9];
  const float* Wxc = (const float*)d_in[10];
  const float* Whc = (const float*)d_in[11];
  const float* bc  = (const float*)d_in[12];
  float* out = (float*)d_out;

  // ws layout: Bws 4 MiB | hbuf 128 KiB (4 buffers) | bar 1 KiB
  unsigned short* Bws  = (unsigned short*)d_ws;
  u64*            hbuf = (u64*)((char*)d_ws + (size_t)4 * 1024 * 1024);
  unsigned*       bar  = (unsigned*)((char*)d_ws + (size_t)4 * 1024 * 1024 + 128 * 1024);

  k_prep<<<1024, TPB, 0, stream>>>(Whi, Whf, Who, Whc, Wxi, Wxf, Wxo, Wxc, Bws, bar);
  k_scan<<<NWG, TPB, 0, stream>>>(x, bi, bfv, bo, bc, Bws, hbuf, bar, out);
}